// Round 8
// baseline (2243.950 us; speedup 1.0000x reference)
//
#include <hip/hip_runtime.h>
#include <math.h>

#define NPTS 16384
#define NCTR 1024
#define BATCH 8
#define NCELL 512  // 8x8x8 Morton cells

typedef unsigned long long u64;
typedef unsigned int u32;

// Bit-exact squared distance matching numpy: ((dx*dx + dy*dy) + dz*dz),
// each op individually IEEE-rounded (no FMA contraction).
__device__ __forceinline__ float sq_dist(float x, float y, float z,
                                         float cx, float cy, float cz) {
  float dx = __fsub_rn(x, cx);
  float dy = __fsub_rn(y, cy);
  float dz = __fsub_rn(z, cz);
  return __fadd_rn(__fadd_rn(__fmul_rn(dx, dx), __fmul_rn(dy, dy)), __fmul_rn(dz, dz));
}

__device__ __forceinline__ float silu_f(float x) {
  return x / (1.0f + __expf(-x));
}

__device__ __forceinline__ u64 kmax(u64 a, u64 b) { return a > b ? a : b; }

__device__ __forceinline__ int morton_cell(float x, float y, float z) {
  int mx = min(7, max(0, (int)(x * 8.0f)));
  int my = min(7, max(0, (int)(y * 8.0f)));
  int mz = min(7, max(0, (int)(z * 8.0f)));
  int m = 0;
#pragma unroll
  for (int k = 0; k < 3; ++k) {
    m |= ((mx >> k) & 1) << (3 * k + 2);
    m |= ((my >> k) & 1) << (3 * k + 1);
    m |= ((mz >> k) & 1) << (3 * k + 0);
  }
  return m;
}

// ---------------------------------------------------------------------------
// Kernel 0: DETERMINISTIC Morton counting sort, one block per batch.
// ---------------------------------------------------------------------------
__global__ __launch_bounds__(1024) void sort_kernel(
    const float* __restrict__ xyz, float* __restrict__ sxg,
    float* __restrict__ syg, float* __restrict__ szg, int* __restrict__ sog) {
  const int b = blockIdx.x, t = threadIdx.x;
  const float* X = xyz + (size_t)b * 3 * NPTS;
  const float* Y = X + NPTS;
  const float* Z = X + 2 * NPTS;
  __shared__ int cnt[NCELL];
  __shared__ int off[NCELL];
  __shared__ int start[NCELL];
  __shared__ int so_l[NPTS];  // 64 KB
  for (int e = t; e < NCELL; e += 1024) cnt[e] = 0;
  __syncthreads();
#pragma unroll
  for (int j = 0; j < 16; ++j) {
    const int n = t + (j << 10);
    atomicAdd(&cnt[morton_cell(X[n], Y[n], Z[n])], 1);
  }
  __syncthreads();
  if (t < NCELL) off[t] = cnt[t];
  __syncthreads();
  for (int d = 1; d < NCELL; d <<= 1) {  // Hillis-Steele inclusive scan
    int v = 0;
    if (t < NCELL) { v = off[t]; if (t >= d) v += off[t - d]; }
    __syncthreads();
    if (t < NCELL) off[t] = v;
    __syncthreads();
  }
  if (t < NCELL) { off[t] -= cnt[t]; start[t] = off[t]; }
  __syncthreads();
  // phase A: racy scatter of orig index (intra-cell order arbitrary)
#pragma unroll
  for (int j = 0; j < 16; ++j) {
    const int n = t + (j << 10);
    const int pos = atomicAdd(&off[morton_cell(X[n], Y[n], Z[n])], 1);
    so_l[pos] = n;
  }
  __syncthreads();
  // phase B: deterministic intra-cell order (ascending orig index)
  if (t < NCELL) {
    const int s0 = start[t], k = cnt[t];
    for (int i2 = 1; i2 < k; ++i2) {
      const int key = so_l[s0 + i2];
      int j2 = i2 - 1;
      while (j2 >= 0 && so_l[s0 + j2] > key) {
        so_l[s0 + j2 + 1] = so_l[s0 + j2];
        --j2;
      }
      so_l[s0 + j2 + 1] = key;
    }
  }
  __syncthreads();
  // phase C: deterministic rebuild
  float* sx = sxg + (size_t)b * NPTS;
  float* sy = syg + (size_t)b * NPTS;
  float* sz = szg + (size_t)b * NPTS;
  int* so = sog + (size_t)b * NPTS;
#pragma unroll
  for (int j = 0; j < 16; ++j) {
    const int pos = t + (j << 10);
    const int n = so_l[pos];
    so[pos] = n;
    sx[pos] = X[n];
    sy[pos] = Y[n];
    sz[pos] = Z[n];
  }
}

// ---------------------------------------------------------------------------
// Kernel 1: bbox-pruned FPS, round 8: halve the wave count (8 x 32ch).
// R7 post-mortem: interleave+guards gave the first real win (1215->1144) but
// per-iter is still ~2680cy. Accounting: the per-iter SKELETON (skip test,
// ballot, slot merge, centroid reads, publish) is ~50 VALU ops/wave; at 16
// waves = 4/SIMD that is ~400cy/SIMD of pure issue serialization + 16-wave
// barrier skew, every iteration, independent of pruning. Skeleton-bound.
// This round: 512 threads, 8 waves x 32 channels.
//  - per-SIMD skeleton issue halves (2 waves/SIMD); 8-wave barrier; 4-deep
//    atomic contention. Early-phase update issue per SIMD UNCHANGED (64
//    channel-updates/SIMD either way).
//  - VGPR: at 8 waves/CU the HW cap is 256/wave (m69: waves halve at
//    64/128/256), so 32x(z,d,lo)=96 + temps fits WITHOUT the R3 spill trap.
//  - all R7 machinery kept: interleaved segments p=(c<<9)+(w<<6)+lane,
//    two-tier guarded updates, rebuild elision, dual sub-slot ds_max_u64,
//    z publish, 3-slot rotation. Index changes: wmaxch=(pos>>9)&31,
//    winner wave=(pu>>6)&7.
// Exactness unchanged (same per-segment boxes, same sound skip test, same
// unique keys -> atomicMax == jnp.argmax tie-order).
// ---------------------------------------------------------------------------
#define CH_LIST(F) \
  F(0)  F(1)  F(2)  F(3)  F(4)  F(5)  F(6)  F(7)  \
  F(8)  F(9)  F(10) F(11) F(12) F(13) F(14) F(15) \
  F(16) F(17) F(18) F(19) F(20) F(21) F(22) F(23) \
  F(24) F(25) F(26) F(27) F(28) F(29) F(30) F(31)

__global__ __launch_bounds__(512)
void fps_kernel(const float* __restrict__ xyz, const float* __restrict__ sxg,
                const float* __restrict__ syg, const float* __restrict__ szg,
                const int* __restrict__ sog, int* __restrict__ fps_idx) {
  const int b = blockIdx.x;
  const int t = threadIdx.x;
  const int w = t >> 6, lane = t & 63;
  const float* X = xyz + (size_t)b * 3 * NPTS;
  const float* Y = X + NPTS;
  const float* Z = X + 2 * NPTS;
  const float* SX = sxg + (size_t)b * NPTS;
  const float* SY = syg + (size_t)b * NPTS;
  const float* SZ = szg + (size_t)b * NPTS;
  const int* SO = sog + (size_t)b * NPTS;

  __shared__ float sxy[2 * NPTS];               // 128 KB interleaved sorted x,y
  __shared__ __align__(16) u64 slot[3][2];      // rotating argmax sub-slots
  __shared__ float s_zw[3][8];                  // [parity][wave] winner z
  __shared__ int fps_lds[NCTR];                 // buffered output indices (4 KB)

  // per-channel state: d (running min dist), lo (CONSTANT key low word
  // (16383-orig)<<14 | pos), z (sorted z of the lane's point)
#define DECL_CH(c) float z##c, d##c; u32 lo##c;
  CH_LIST(DECL_CH)
#undef DECL_CH

  const int wbase = (w << 6) + lane;  // interleaved mapping base (8 waves)

  // lane-indexed channel bboxes: lane c (c<32) holds channel c's bbox.
  float bmnx = __builtin_inff(), bmxx = -__builtin_inff();
  float bmny = __builtin_inff(), bmxy = -__builtin_inff();
  float bmnz = __builtin_inff(), bmxz = -__builtin_inff();

#define INIT_CH(c)                                              \
  {                                                             \
    const int p = ((c) << 9) + wbase;                           \
    const float xv = SX[p], yv = SY[p], zv = SZ[p];             \
    sxy[2 * p] = xv; sxy[2 * p + 1] = yv;                       \
    z##c = zv;                                                  \
    const int o = SO[p];                                        \
    lo##c = ((u32)(16383 - o) << 14) | (u32)p;                  \
    d##c = __builtin_inff();                                    \
    float mnx = xv, mxx = xv, mny = yv, mxy = yv;               \
    float mnz = zv, mxz = zv;                                   \
    _Pragma("unroll")                                           \
    for (int off = 32; off >= 1; off >>= 1) {                   \
      mnx = fminf(mnx, __shfl_xor(mnx, off));                   \
      mxx = fmaxf(mxx, __shfl_xor(mxx, off));                   \
      mny = fminf(mny, __shfl_xor(mny, off));                   \
      mxy = fmaxf(mxy, __shfl_xor(mxy, off));                   \
      mnz = fminf(mnz, __shfl_xor(mnz, off));                   \
      mxz = fmaxf(mxz, __shfl_xor(mxz, off));                   \
    }                                                           \
    if (lane == (c)) {                                          \
      bmnx = mnx; bmxx = mxx; bmny = mny;                       \
      bmxy = mxy; bmnz = mnz; bmxz = mxz;                       \
    }                                                           \
  }
  CH_LIST(INIT_CH)
#undef INIT_CH

#define PIN_CH(c) asm volatile("" : "+v"(z##c));
  CH_LIST(PIN_CH)
#undef PIN_CH

  if (t < 6) slot[t / 2][t & 1] = 0ull;
  if (t == 0) fps_lds[0] = 0;
  __syncthreads();  // LDS staging complete, slots zeroed

  // first centroid = original point 0 (uniform loads)
  float cx = X[0], cy = Y[0], cz = Z[0];
  float gd = __builtin_inff();          // wave max dist (exact at all times)
  u64 gkey = 0ull;                      // packed key, valid after 1st rebuild
  float gz = 0.0f;                      // z of wave-max point
  int wmaxch = 0;                       // channel holding the wave max

  // pack channel c's key on demand (low word constant)
#define MK(c) ((((u64)__float_as_uint(d##c)) << 32) | (u64)lo##c)
  // key/z select: one compare drives both
#define KSEL(ka, za, kb, zb, ko, zo)          \
  {                                           \
    const u64 ka_ = (ka), kb_ = (kb);         \
    const bool g_ = ka_ > kb_;                \
    ko = g_ ? ka_ : kb_;                      \
    zo = g_ ? (za) : (zb);                    \
  }

  for (int i = 1; i < NCTR; ++i) {
    // per-channel conservative skip tests, lanes 0..31 in parallel
    // (lanes >=32 have inf-boxes -> lb=+inf -> always "skip" -> bit 0).
    const float ux = fmaxf(fmaxf(__fsub_rn(bmnx, cx), __fsub_rn(cx, bmxx)), 0.0f);
    const float uy = fmaxf(fmaxf(__fsub_rn(bmny, cy), __fsub_rn(cy, bmxy)), 0.0f);
    const float uz = fmaxf(fmaxf(__fsub_rn(bmnz, cz), __fsub_rn(cz, bmxz)), 0.0f);
    const float lb = __fadd_rn(__fadd_rn(__fmul_rn(ux, ux), __fmul_rn(uy, uy)),
                               __fmul_rn(uz, uz));
    const u32 mask = (u32)__ballot(!(__fmul_rn(lb, 0.9999f) >= gd));
    if (mask != 0u) {
      if (__builtin_popcount(mask) >= 12) {
        // batched path (early phase): all 32 ds_reads pipelined
#define UPDU_CH(c)                                                       \
        {                                                                \
          const float2 xy =                                              \
              *(const float2*)(sxy + 2 * (((c) << 9) + wbase));          \
          const float dd = sq_dist(xy.x, xy.y, z##c, cx, cy, cz);        \
          d##c = fminf(d##c, dd);                                        \
        }
        CH_LIST(UPDU_CH)
#undef UPDU_CH
      } else {
        // guarded path (late phase): scalar branch per channel; volatile
        // pin keeps the body un-speculated so skipped channels cost ~2 SALU
#define UPDG_CH(c)                                                       \
        if (mask & (1u << (c))) {                                        \
          const float2 xy =                                              \
              *(const float2*)(sxy + 2 * (((c) << 9) + wbase));          \
          float dd = sq_dist(xy.x, xy.y, z##c, cx, cy, cz);              \
          asm volatile("" : "+v"(dd));                                   \
          d##c = fminf(d##c, dd);                                        \
        }
        CH_LIST(UPDG_CH)
#undef UPDG_CH
      }
      // rebuild only if the max-holding channel might have shrunk
      if ((mask >> wmaxch) & 1u) {
        u64 ka0, ka1, ka2, ka3, ka4, ka5, ka6, ka7;
        u64 ka8, ka9, ka10, ka11, ka12, ka13, ka14, ka15;
        float fa0, fa1, fa2, fa3, fa4, fa5, fa6, fa7;
        float fa8, fa9, fa10, fa11, fa12, fa13, fa14, fa15;
        KSEL(MK(0), z0, MK(1), z1, ka0, fa0)
        KSEL(MK(2), z2, MK(3), z3, ka1, fa1)
        KSEL(MK(4), z4, MK(5), z5, ka2, fa2)
        KSEL(MK(6), z6, MK(7), z7, ka3, fa3)
        KSEL(MK(8), z8, MK(9), z9, ka4, fa4)
        KSEL(MK(10), z10, MK(11), z11, ka5, fa5)
        KSEL(MK(12), z12, MK(13), z13, ka6, fa6)
        KSEL(MK(14), z14, MK(15), z15, ka7, fa7)
        KSEL(MK(16), z16, MK(17), z17, ka8, fa8)
        KSEL(MK(18), z18, MK(19), z19, ka9, fa9)
        KSEL(MK(20), z20, MK(21), z21, ka10, fa10)
        KSEL(MK(22), z22, MK(23), z23, ka11, fa11)
        KSEL(MK(24), z24, MK(25), z25, ka12, fa12)
        KSEL(MK(26), z26, MK(27), z27, ka13, fa13)
        KSEL(MK(28), z28, MK(29), z29, ka14, fa14)
        KSEL(MK(30), z30, MK(31), z31, ka15, fa15)
        u64 kb0, kb1, kb2, kb3, kb4, kb5, kb6, kb7;
        float fb0, fb1, fb2, fb3, fb4, fb5, fb6, fb7;
        KSEL(ka0, fa0, ka1, fa1, kb0, fb0)
        KSEL(ka2, fa2, ka3, fa3, kb1, fb1)
        KSEL(ka4, fa4, ka5, fa5, kb2, fb2)
        KSEL(ka6, fa6, ka7, fa7, kb3, fb3)
        KSEL(ka8, fa8, ka9, fa9, kb4, fb4)
        KSEL(ka10, fa10, ka11, fa11, kb5, fb5)
        KSEL(ka12, fa12, ka13, fa13, kb6, fb6)
        KSEL(ka14, fa14, ka15, fa15, kb7, fb7)
        u64 kc0, kc1, kc2, kc3;
        float fc0, fc1, fc2, fc3;
        KSEL(kb0, fb0, kb1, fb1, kc0, fc0)
        KSEL(kb2, fb2, kb3, fb3, kc1, fc1)
        KSEL(kb4, fb4, kb5, fb5, kc2, fc2)
        KSEL(kb6, fb6, kb7, fb7, kc3, fc3)
        u64 kd0, kd1, kk;
        float fd0, fd1, bz;
        KSEL(kc0, fc0, kc1, fc1, kd0, fd0)
        KSEL(kc2, fc2, kc3, fc3, kd1, fd1)
        KSEL(kd0, fd0, kd1, fd1, kk, bz)
        // wave argmax butterfly over (key, z)
#pragma unroll
        for (int off = 32; off >= 1; off >>= 1) {
          const u64 ok = __shfl_xor(kk, off);
          const float oz = __shfl_xor(bz, off);
          const bool g_ = ok > kk;
          kk = g_ ? ok : kk;
          bz = g_ ? oz : bz;
        }
        gkey = kk;
        gz = bz;
        gd = __uint_as_float((u32)(gkey >> 32));
        wmaxch = (int)(((u32)gkey >> 9) & 31u);  // pos bits 9..13 = channel
      }
    }
    const int si = i % 3;
    if (lane == 0) {
      s_zw[si][w] = gz;                       // publish wave-winner z
      atomicMax(&slot[si][w & 1], gkey);      // dual sub-slot ds_max_u64
    }
    if (t == 0) {                             // pre-zero next parity
      const int nsi = si == 2 ? 0 : si + 1;
      slot[nsi][0] = 0ull;
      slot[nsi][1] = 0ull;
    }
    __syncthreads();  // the ONLY barrier per step

    const u64 m = kmax(slot[si][0], slot[si][1]);  // merge sub-slots
    const u32 lowb = (u32)m;
    const int pw = (int)(lowb & 0x3FFFu);  // winner's sorted position
    if (t == 0) fps_lds[i] = 16383 - (int)((lowb >> 14) & 0x3FFFu);

    const int pu = __builtin_amdgcn_readfirstlane(pw);
    const float2 cxy = *(const float2*)(sxy + 2 * pu);  // ds_read_b64
    cx = cxy.x;
    cy = cxy.y;
    cz = s_zw[si][(pu >> 6) & 7];  // winner wave under interleaved mapping
  }
#undef MK
#undef KSEL

  __syncthreads();
  // bulk writeout of buffered indices
  for (int e = t; e < NCTR; e += 512) fps_idx[b * NCTR + e] = fps_lds[e];
}

// ---------------------------------------------------------------------------
// Kernel 2: ball query. One wave per centroid; scan points in ascending index
// order, collect first 32 with dist <= r^2, pad with first hit.
// ---------------------------------------------------------------------------
__global__ __launch_bounds__(256) void ballq_kernel(const float* __restrict__ xyz,
                                                    const int* __restrict__ fps_idx,
                                                    int* __restrict__ ball_idx) {
  const int gw = (blockIdx.x * 256 + threadIdx.x) >> 6;  // 0..8191
  const int lane = threadIdx.x & 63;
  const int b = gw >> 10;
  const float* X = xyz + (size_t)b * 3 * NPTS;
  const float* Y = X + NPTS;
  const float* Z = X + 2 * NPTS;
  const int c = fps_idx[gw];
  const float cx = X[c], cy = Y[c], cz = Z[c];
  int* out = ball_idx + (size_t)gw * 32;
  const float R2 = 0.04f;

  int cnt = 0, first = -1;
  for (int base = 0; base < NPTS; base += 64) {
    const int j = base + lane;
    const float d = sq_dist(X[j], Y[j], Z[j], cx, cy, cz);
    const bool inb = !(d > R2);
    const unsigned long long m = __ballot(inb);
    if (first < 0 && m != 0ull) first = base + __ffsll(m) - 1;
    if (inb) {
      const int pos = cnt + __popcll(m & ((1ull << lane) - 1ull));
      if (pos < 32) out[pos] = j;
    }
    cnt += __popcll(m);
    if (cnt >= 32) break;
  }
  for (int k = cnt + lane; k < 32; k += 64) out[k] = first;
}

// ---------------------------------------------------------------------------
// Kernel 2b: one-off weight transpose into workspace: wt[c][o] layouts.
// ---------------------------------------------------------------------------
__global__ __launch_bounds__(256) void transpose_w_kernel(
    const float* __restrict__ w0, const float* __restrict__ w1,
    const float* __restrict__ w2, float* __restrict__ wt0,
    float* __restrict__ wt1, float* __restrict__ wt2) {
  const int t0 = blockIdx.x * 256 + threadIdx.x;
  const int stride = gridDim.x * 256;
  for (int e = t0; e < 64 * 67; e += stride) {
    int o = e / 67, c = e - o * 67;
    wt0[c * 64 + o] = w0[e];
  }
  for (int e = t0; e < 128 * 64; e += stride) {
    int o = e >> 6, c = e & 63;
    wt1[c * 128 + o] = w1[e];
  }
  for (int e = t0; e < 256 * 128; e += stride) {
    int o = e >> 7, c = e & 127;
    wt2[c * 256 + o] = w2[e];
  }
}

// ---------------------------------------------------------------------------
// Kernel 3: fused gather + 3-layer pointwise MLP + mean over 32 samples.
// ---------------------------------------------------------------------------
__global__ __launch_bounds__(256, 2) void mlp_kernel(
    const float* __restrict__ xyz, const float* __restrict__ points,
    const int* __restrict__ fps_idx, const int* __restrict__ ball_idx,
    const float* __restrict__ wt0, const float* __restrict__ b0,
    const float* __restrict__ wt1, const float* __restrict__ b1,
    const float* __restrict__ wt2, const float* __restrict__ b2,
    float* __restrict__ out) {
  const int s = blockIdx.x, b = blockIdx.y, t = threadIdx.x;

  __shared__ float A1[64 * 36];    // layer0 out [o][k]
  __shared__ float A2[128 * 36];   // layer1 out [o][k]
  __shared__ float S[8704];        // scratch: A0+Wt0 | Wt1 | Wt2 chunk
  __shared__ float bias_sh[256];
  __shared__ int jidx[32];
  __shared__ float ctr[3];

  const int g = b * NCTR + s;

  // phase 1: indices, centroid, Wt0 [67][68] (stride-1 writes), bias0
  if (t < 32) jidx[t] = ball_idx[(size_t)g * 32 + t];
  if (t < 3) ctr[t] = xyz[((size_t)b * 3 + t) * NPTS + fps_idx[g]];
  float* A0 = S;              // [67][36]
  float* Wt0 = S + 67 * 36;   // [67][68]
  for (int e = t; e < 67 * 64; e += 256) {
    int c = e >> 6, o = e & 63;
    Wt0[c * 68 + o] = wt0[e];  // global coalesced, LDS stride-1
  }
  if (t < 64) bias_sh[t] = b0[t];
  __syncthreads();

  // phase 2: gather A0 = [xyz_norm(3); points(64)] x 32 samples
  for (int e = t; e < 67 * 32; e += 256) {
    int c = e >> 5, k = e & 31;
    int j = jidx[k];
    float v;
    if (c < 3)
      v = xyz[((size_t)b * 3 + c) * NPTS + j] - ctr[c];
    else
      v = points[((size_t)b * 64 + (c - 3)) * NPTS + j];
    A0[c * 36 + k] = v;
  }
  __syncthreads();

  // phase 3: layer 0 (67 -> 64), tile 4k x 2o
  {
    const int o0 = (t & 31) * 2;
    const int k0 = (t >> 5) * 4;
    float acc[4][2] = {{0.f, 0.f}, {0.f, 0.f}, {0.f, 0.f}, {0.f, 0.f}};
    for (int c = 0; c < 67; ++c) {
      const float4 a = *(const float4*)(A0 + c * 36 + k0);
      const float wv0 = Wt0[c * 68 + o0];
      const float wv1 = Wt0[c * 68 + o0 + 1];
      acc[0][0] = fmaf(a.x, wv0, acc[0][0]);
      acc[1][0] = fmaf(a.y, wv0, acc[1][0]);
      acc[2][0] = fmaf(a.z, wv0, acc[2][0]);
      acc[3][0] = fmaf(a.w, wv0, acc[3][0]);
      acc[0][1] = fmaf(a.x, wv1, acc[0][1]);
      acc[1][1] = fmaf(a.y, wv1, acc[1][1]);
      acc[2][1] = fmaf(a.z, wv1, acc[2][1]);
      acc[3][1] = fmaf(a.w, wv1, acc[3][1]);
    }
#pragma unroll
    for (int i = 0; i < 2; ++i) {
      const float bb = bias_sh[o0 + i];
      float4 r;
      r.x = silu_f(acc[0][i] + bb);
      r.y = silu_f(acc[1][i] + bb);
      r.z = silu_f(acc[2][i] + bb);
      r.w = silu_f(acc[3][i] + bb);
      *(float4*)(A1 + (o0 + i) * 36 + k0) = r;
    }
  }
  __syncthreads();

  // phase 4: stage Wt1 [64][132] (stride-1 writes), bias1
  float* Wt1 = S;
  for (int e = t; e < 128 * 64; e += 256) {
    int c = e >> 7, o = e & 127;
    Wt1[c * 132 + o] = wt1[e];
  }
  if (t < 128) bias_sh[t] = b1[t];
  __syncthreads();

  // phase 5: layer 1 (64 -> 128), tile 4k x 4o
  {
    const int o0 = (t & 31) * 4;
    const int k0 = (t >> 5) * 4;
    float acc[4][4];
#pragma unroll
    for (int kk = 0; kk < 4; ++kk)
#pragma unroll
      for (int oo = 0; oo < 4; ++oo) acc[kk][oo] = 0.f;
    for (int c = 0; c < 64; ++c) {
      const float4 a = *(const float4*)(A1 + c * 36 + k0);
      const float4 w = *(const float4*)(Wt1 + c * 132 + o0);
      const float av[4] = {a.x, a.y, a.z, a.w};
      const float wv[4] = {w.x, w.y, w.z, w.w};
#pragma unroll
      for (int kk = 0; kk < 4; ++kk)
#pragma unroll
        for (int oo = 0; oo < 4; ++oo)
          acc[kk][oo] = fmaf(av[kk], wv[oo], acc[kk][oo]);
    }
#pragma unroll
    for (int oo = 0; oo < 4; ++oo) {
      const float bb = bias_sh[o0 + oo];
      float4 r;
      r.x = silu_f(acc[0][oo] + bb);
      r.y = silu_f(acc[1][oo] + bb);
      r.z = silu_f(acc[2][oo] + bb);
      r.w = silu_f(acc[3][oo] + bb);
      *(float4*)(A2 + (o0 + oo) * 36 + k0) = r;
    }
  }
  __syncthreads();

  // phase 6: layer 2 (128 -> 256) in 4 chunks of 64 outputs + mean over k
  float* Wt2 = S;   // [128][68] per chunk
  float* P = A1;    // partial sums [64][9] (A1 dead)
  const int o0 = (t & 31) * 2;
  const int k0 = (t >> 5) * 4;
  const int kg = t >> 5;
  for (int chunk = 0; chunk < 4; ++chunk) {
    for (int e = t; e < 64 * 128; e += 256) {
      int c = e >> 6, o = e & 63;
      Wt2[c * 68 + o] = wt2[c * 256 + chunk * 64 + o];  // coalesced / stride-1
    }
    if (t < 64) bias_sh[t] = b2[chunk * 64 + t];
    __syncthreads();

    float acc[4][2] = {{0.f, 0.f}, {0.f, 0.f}, {0.f, 0.f}, {0.f, 0.f}};
    for (int c = 0; c < 128; ++c) {
      const float4 a = *(const float4*)(A2 + c * 36 + k0);
      const float wv0 = Wt2[c * 68 + o0];
      const float wv1 = Wt2[c * 68 + o0 + 1];
      acc[0][0] = fmaf(a.x, wv0, acc[0][0]);
      acc[1][0] = fmaf(a.y, wv0, acc[1][0]);
      acc[2][0] = fmaf(a.z, wv0, acc[2][0]);
      acc[3][0] = fmaf(a.w, wv0, acc[3][0]);
      acc[0][1] = fmaf(a.x, wv1, acc[0][1]);
      acc[1][1] = fmaf(a.y, wv1, acc[1][1]);
      acc[2][1] = fmaf(a.z, wv1, acc[2][1]);
      acc[3][1] = fmaf(a.w, wv1, acc[3][1]);
    }
#pragma unroll
    for (int i = 0; i < 2; ++i) {
      const float bb = bias_sh[o0 + i];
      float sum = silu_f(acc[0][i] + bb) + silu_f(acc[1][i] + bb) +
                  silu_f(acc[2][i] + bb) + silu_f(acc[3][i] + bb);
      P[(o0 + i) * 9 + kg] = sum;
    }
    __syncthreads();
    if (t < 64) {
      float tot = 0.f;
#pragma unroll
      for (int q = 0; q < 8; ++q) tot += P[t * 9 + q];
      out[((size_t)b * 256 + chunk * 64 + t) * NCTR + s] = tot * (1.0f / 32.0f);
    }
    __syncthreads();
  }
}

extern "C" void kernel_launch(void* const* d_in, const int* in_sizes, int n_in,
                              void* d_out, int out_size, void* d_ws, size_t ws_size,
                              hipStream_t stream) {
  const float* xyz = (const float*)d_in[0];
  const float* points = (const float*)d_in[1];
  const float* w0 = (const float*)d_in[2];
  const float* b0 = (const float*)d_in[3];
  const float* w1 = (const float*)d_in[4];
  const float* b1 = (const float*)d_in[5];
  const float* w2 = (const float*)d_in[6];
  const float* b2 = (const float*)d_in[7];
  float* out = (float*)d_out;

  int* fps = (int*)d_ws;                       // 8K ints
  int* bidx = (int*)d_ws + 8192;               // 256K ints
  float* wt0 = (float*)d_ws + 270336;          // 67*64
  float* wt1 = wt0 + 67 * 64;                  // 64*128
  float* wt2 = wt1 + 64 * 128;                 // 128*256
  float* sxg = (float*)d_ws + 315584;          // 8*16384 sorted x
  float* syg = sxg + BATCH * NPTS;             // sorted y
  float* szg = syg + BATCH * NPTS;             // sorted z
  int* sog = (int*)(szg + BATCH * NPTS);       // sorted orig idx (~3.4 MB total)

  transpose_w_kernel<<<64, 256, 0, stream>>>(w0, w1, w2, wt0, wt1, wt2);
  sort_kernel<<<BATCH, 1024, 0, stream>>>(xyz, sxg, syg, szg, sog);
  fps_kernel<<<BATCH, 512, 0, stream>>>(xyz, sxg, syg, szg, sog, fps);
  ballq_kernel<<<2048, 256, 0, stream>>>(xyz, fps, bidx);
  mlp_kernel<<<dim3(NCTR, BATCH), 256, 0, stream>>>(xyz, points, fps, bidx,
                                                    wt0, b0, wt1, b1, wt2, b2, out);
}

// Round 9
// 1863.700 us; speedup vs baseline: 1.2040x; 1.2040x over previous
//
#include <hip/hip_runtime.h>
#include <math.h>

#define NPTS 16384
#define NCTR 1024
#define BATCH 8
#define NCELL 512  // 8x8x8 Morton cells

typedef unsigned long long u64;
typedef unsigned int u32;

// Bit-exact squared distance matching numpy: ((dx*dx + dy*dy) + dz*dz),
// each op individually IEEE-rounded (no FMA contraction).
__device__ __forceinline__ float sq_dist(float x, float y, float z,
                                         float cx, float cy, float cz) {
  float dx = __fsub_rn(x, cx);
  float dy = __fsub_rn(y, cy);
  float dz = __fsub_rn(z, cz);
  return __fadd_rn(__fadd_rn(__fmul_rn(dx, dx), __fmul_rn(dy, dy)), __fmul_rn(dz, dz));
}

__device__ __forceinline__ float silu_f(float x) {
  return x / (1.0f + __expf(-x));
}

__device__ __forceinline__ u64 kmax(u64 a, u64 b) { return a > b ? a : b; }

__device__ __forceinline__ int morton_cell(float x, float y, float z) {
  int mx = min(7, max(0, (int)(x * 8.0f)));
  int my = min(7, max(0, (int)(y * 8.0f)));
  int mz = min(7, max(0, (int)(z * 8.0f)));
  int m = 0;
#pragma unroll
  for (int k = 0; k < 3; ++k) {
    m |= ((mx >> k) & 1) << (3 * k + 2);
    m |= ((my >> k) & 1) << (3 * k + 1);
    m |= ((mz >> k) & 1) << (3 * k + 0);
  }
  return m;
}

// ---------------------------------------------------------------------------
// Kernel 0: DETERMINISTIC Morton counting sort, one block per batch.
// R9: phase A scatters in 16 ORDERED rounds (barrier between rounds), so each
// cell's content is nearly-sorted by orig index (inversions only within a
// round, ~2/cell). Phase B's serial insertion sort (latency-chained LDS,
// ~120cy/dependent op) then runs in ~O(k) instead of O(k^2/4). Phase B is
// unchanged -> final order (ascending orig idx per cell) and determinism
// are unchanged.
// ---------------------------------------------------------------------------
__global__ __launch_bounds__(1024) void sort_kernel(
    const float* __restrict__ xyz, float* __restrict__ sxg,
    float* __restrict__ syg, float* __restrict__ szg, int* __restrict__ sog) {
  const int b = blockIdx.x, t = threadIdx.x;
  const float* X = xyz + (size_t)b * 3 * NPTS;
  const float* Y = X + NPTS;
  const float* Z = X + 2 * NPTS;
  __shared__ int cnt[NCELL];
  __shared__ int off[NCELL];
  __shared__ int start[NCELL];
  __shared__ int so_l[NPTS];  // 64 KB
  for (int e = t; e < NCELL; e += 1024) cnt[e] = 0;
  __syncthreads();
#pragma unroll
  for (int j = 0; j < 16; ++j) {
    const int n = t + (j << 10);
    atomicAdd(&cnt[morton_cell(X[n], Y[n], Z[n])], 1);
  }
  __syncthreads();
  if (t < NCELL) off[t] = cnt[t];
  __syncthreads();
  for (int d = 1; d < NCELL; d <<= 1) {  // Hillis-Steele inclusive scan
    int v = 0;
    if (t < NCELL) { v = off[t]; if (t >= d) v += off[t - d]; }
    __syncthreads();
    if (t < NCELL) off[t] = v;
    __syncthreads();
  }
  if (t < NCELL) { off[t] -= cnt[t]; start[t] = off[t]; }
  __syncthreads();
  // phase A: ORDERED scatter in 16 rounds -> nearly-sorted cell contents
  for (int j = 0; j < 16; ++j) {
    const int n = t + (j << 10);
    const int pos = atomicAdd(&off[morton_cell(X[n], Y[n], Z[n])], 1);
    so_l[pos] = n;
    __syncthreads();
  }
  // phase B: deterministic intra-cell order (ascending orig index);
  // input nearly-sorted -> ~O(k) with few shifts
  if (t < NCELL) {
    const int s0 = start[t], k = cnt[t];
    for (int i2 = 1; i2 < k; ++i2) {
      const int key = so_l[s0 + i2];
      int j2 = i2 - 1;
      while (j2 >= 0 && so_l[s0 + j2] > key) {
        so_l[s0 + j2 + 1] = so_l[s0 + j2];
        --j2;
      }
      so_l[s0 + j2 + 1] = key;
    }
  }
  __syncthreads();
  // phase C: deterministic rebuild
  float* sx = sxg + (size_t)b * NPTS;
  float* sy = syg + (size_t)b * NPTS;
  float* sz = szg + (size_t)b * NPTS;
  int* so = sog + (size_t)b * NPTS;
#pragma unroll
  for (int j = 0; j < 16; ++j) {
    const int pos = t + (j << 10);
    const int n = so_l[pos];
    so[pos] = n;
    sx[pos] = X[n];
    sy[pos] = Y[n];
    sz[pos] = Z[n];
  }
}

// ---------------------------------------------------------------------------
// Kernel 1: bbox-pruned FPS — R7 configuration (the measured best: 1144us).
// R8 post-mortem: 8 waves x 32 channels REGRESSED (1420us, no spill): with 2
// waves/SIMD the per-wave latency chain (slot merge -> centroid reads ->
// test -> updates -> deeper rebuild tree -> butterfly) lost its TLP cover.
// 16 waves x 16 channels is the sweet spot (vs 1217 blocked, 1420 8-wave).
// Structure: interleaved segments p=(c<<10)+(w<<6)+lane; per-channel scalar
// guards w/ volatile pin; two-tier dispatch (popcount>=6 -> batched);
// d-as-float updates; rebuild elision; dual sub-slot ds_max_u64; z publish
// via s_zw; 3-slot rotation; LDS-buffered output.
// Exactness: per-channel skip test sound (lb <= rounded dist for all q in
// channel box, d_q <= gd, 0.9999 margin); fminf == u64-min with constant
// low word; unique keys -> atomicMax winner == jnp.argmax tie-order.
// ---------------------------------------------------------------------------
#define CH_LIST(F) \
  F(0,a0)  F(1,a1)  F(2,a2)  F(3,a3)  F(4,a0)  F(5,a1)  F(6,a2)  F(7,a3)  \
  F(8,a0)  F(9,a1)  F(10,a2) F(11,a3) F(12,a0) F(13,a1) F(14,a2) F(15,a3)

__global__ __launch_bounds__(1024)
void fps_kernel(const float* __restrict__ xyz, const float* __restrict__ sxg,
                const float* __restrict__ syg, const float* __restrict__ szg,
                const int* __restrict__ sog, int* __restrict__ fps_idx) {
  const int b = blockIdx.x;
  const int t = threadIdx.x;
  const int w = t >> 6, lane = t & 63;
  const float* X = xyz + (size_t)b * 3 * NPTS;
  const float* Y = X + NPTS;
  const float* Z = X + 2 * NPTS;
  const float* SX = sxg + (size_t)b * NPTS;
  const float* SY = syg + (size_t)b * NPTS;
  const float* SZ = szg + (size_t)b * NPTS;
  const int* SO = sog + (size_t)b * NPTS;

  __shared__ float sxy[2 * NPTS];               // 128 KB interleaved sorted x,y
  __shared__ __align__(16) u64 slot[3][2];      // rotating argmax sub-slots
  __shared__ float s_zw[3][16];                 // [parity][wave] winner z
  __shared__ int fps_lds[NCTR];                 // buffered output indices (4 KB)

  // per-channel state: d (running min dist, float), lo (CONSTANT key low
  // word (16383-orig)<<14 | pos), z (sorted z of the lane's point)
#define DECL_CH(c, acc) float z##c, d##c; u32 lo##c;
  CH_LIST(DECL_CH)
#undef DECL_CH

  const int wbase = (w << 6) + lane;  // INTERLEAVED mapping base

  // lane-indexed channel bboxes: lane c (c<16) holds channel c's bbox.
  float bmnx = __builtin_inff(), bmxx = -__builtin_inff();
  float bmny = __builtin_inff(), bmxy = -__builtin_inff();
  float bmnz = __builtin_inff(), bmxz = -__builtin_inff();

#define INIT_CH(c, acc)                                         \
  {                                                             \
    const int p = ((c) << 10) + wbase;                          \
    const float xv = SX[p], yv = SY[p], zv = SZ[p];             \
    sxy[2 * p] = xv; sxy[2 * p + 1] = yv;                       \
    z##c = zv;                                                  \
    const int o = SO[p];                                        \
    lo##c = ((u32)(16383 - o) << 14) | (u32)p;                  \
    d##c = __builtin_inff();                                    \
    float mnx = xv, mxx = xv, mny = yv, mxy = yv;               \
    float mnz = zv, mxz = zv;                                   \
    _Pragma("unroll")                                           \
    for (int off = 32; off >= 1; off >>= 1) {                   \
      mnx = fminf(mnx, __shfl_xor(mnx, off));                   \
      mxx = fmaxf(mxx, __shfl_xor(mxx, off));                   \
      mny = fminf(mny, __shfl_xor(mny, off));                   \
      mxy = fmaxf(mxy, __shfl_xor(mxy, off));                   \
      mnz = fminf(mnz, __shfl_xor(mnz, off));                   \
      mxz = fmaxf(mxz, __shfl_xor(mxz, off));                   \
    }                                                           \
    if (lane == c) {                                            \
      bmnx = mnx; bmxx = mxx; bmny = mny;                       \
      bmxy = mxy; bmnz = mnz; bmxz = mxz;                       \
    }                                                           \
  }
  CH_LIST(INIT_CH)
#undef INIT_CH

#define PIN_CH(c, acc) asm volatile("" : "+v"(z##c));
  CH_LIST(PIN_CH)
#undef PIN_CH

  if (t < 6) slot[t / 2][t & 1] = 0ull;
  if (t == 0) fps_lds[0] = 0;
  __syncthreads();  // LDS staging complete, slots zeroed

  // first centroid = original point 0 (uniform loads)
  float cx = X[0], cy = Y[0], cz = Z[0];
  float gd = __builtin_inff();          // wave max dist (exact at all times)
  u64 gkey = 0ull;                      // packed key, valid after 1st rebuild
  float gz = 0.0f;                      // z of wave-max point
  int wmaxch = 0;                       // channel holding the wave max

  // pack channel c's key on demand (low word constant)
#define MK(c) ((((u64)__float_as_uint(d##c)) << 32) | (u64)lo##c)
  // key/z select: one compare drives both
#define KSEL(ka, za, kb, zb, ko, zo)          \
  {                                           \
    const u64 ka_ = (ka), kb_ = (kb);         \
    const bool g_ = ka_ > kb_;                \
    ko = g_ ? ka_ : kb_;                      \
    zo = g_ ? (za) : (zb);                    \
  }

  for (int i = 1; i < NCTR; ++i) {
    // per-channel conservative skip tests, lanes 0..15 in parallel
    // (lanes >=16 have inf-boxes -> lb=+inf -> always "skip").
    const float ux = fmaxf(fmaxf(__fsub_rn(bmnx, cx), __fsub_rn(cx, bmxx)), 0.0f);
    const float uy = fmaxf(fmaxf(__fsub_rn(bmny, cy), __fsub_rn(cy, bmxy)), 0.0f);
    const float uz = fmaxf(fmaxf(__fsub_rn(bmnz, cz), __fsub_rn(cz, bmxz)), 0.0f);
    const float lb = __fadd_rn(__fadd_rn(__fmul_rn(ux, ux), __fmul_rn(uy, uy)),
                               __fmul_rn(uz, uz));
    const u32 mask = (u32)__ballot(!(__fmul_rn(lb, 0.9999f) >= gd));
    if (mask != 0u) {
      if (__builtin_popcount(mask) >= 6) {
        // batched path (early phase): all 16 ds_reads pipelined by compiler
#define UPDU_CH(c, acc)                                                  \
        {                                                                \
          const float2 xy =                                              \
              *(const float2*)(sxy + 2 * (((c) << 10) + wbase));         \
          const float dd = sq_dist(xy.x, xy.y, z##c, cx, cy, cz);        \
          d##c = fminf(d##c, dd);                                        \
        }
        CH_LIST(UPDU_CH)
#undef UPDU_CH
      } else {
        // guarded path (late phase): scalar branch per channel; volatile
        // pin keeps the body un-speculated so skipped channels cost ~2 SALU
#define UPDG_CH(c, acc)                                                  \
        if (mask & (1u << (c))) {                                        \
          const float2 xy =                                              \
              *(const float2*)(sxy + 2 * (((c) << 10) + wbase));         \
          float dd = sq_dist(xy.x, xy.y, z##c, cx, cy, cz);              \
          asm volatile("" : "+v"(dd));                                   \
          d##c = fminf(d##c, dd);                                        \
        }
        CH_LIST(UPDG_CH)
#undef UPDG_CH
      }
      // rebuild only if the max-holding channel might have shrunk
      if ((mask >> wmaxch) & 1u) {
        u64 m0, m1, m2, m3, m4, m5, m6, m7, q0, q1, q2, q3, h0, h1, kk;
        float n0, n1, n2, n3, n4, n5, n6, n7, r0, r1, r2, r3, e0, e1, bz;
        KSEL(MK(0), z0, MK(1), z1, m0, n0)    KSEL(MK(2), z2, MK(3), z3, m1, n1)
        KSEL(MK(4), z4, MK(5), z5, m2, n2)    KSEL(MK(6), z6, MK(7), z7, m3, n3)
        KSEL(MK(8), z8, MK(9), z9, m4, n4)    KSEL(MK(10), z10, MK(11), z11, m5, n5)
        KSEL(MK(12), z12, MK(13), z13, m6, n6) KSEL(MK(14), z14, MK(15), z15, m7, n7)
        KSEL(m0, n0, m1, n1, q0, r0)  KSEL(m2, n2, m3, n3, q1, r1)
        KSEL(m4, n4, m5, n5, q2, r2)  KSEL(m6, n6, m7, n7, q3, r3)
        KSEL(q0, r0, q1, r1, h0, e0)  KSEL(q2, r2, q3, r3, h1, e1)
        KSEL(h0, e0, h1, e1, kk, bz)
        // wave argmax butterfly over (key, z)
#pragma unroll
        for (int off = 32; off >= 1; off >>= 1) {
          const u64 ok = __shfl_xor(kk, off);
          const float oz = __shfl_xor(bz, off);
          const bool g_ = ok > kk;
          kk = g_ ? ok : kk;
          bz = g_ ? oz : bz;
        }
        gkey = kk;
        gz = bz;
        gd = __uint_as_float((u32)(gkey >> 32));
        wmaxch = (int)(((u32)gkey >> 10) & 15u);  // pos bits 10..13 = channel
      }
    }
    const int si = i % 3;
    if (lane == 0) {
      s_zw[si][w] = gz;                       // publish wave-winner z
      atomicMax(&slot[si][w & 1], gkey);      // dual sub-slot ds_max_u64
    }
    if (t == 0) {                             // pre-zero next parity
      const int nsi = si == 2 ? 0 : si + 1;
      slot[nsi][0] = 0ull;
      slot[nsi][1] = 0ull;
    }
    __syncthreads();  // the ONLY barrier per step

    const u64 m = kmax(slot[si][0], slot[si][1]);  // merge sub-slots
    const u32 lowb = (u32)m;
    const int pw = (int)(lowb & 0x3FFFu);  // winner's sorted position
    if (t == 0) fps_lds[i] = 16383 - (int)((lowb >> 14) & 0x3FFFu);

    const int pu = __builtin_amdgcn_readfirstlane(pw);
    const float2 cxy = *(const float2*)(sxy + 2 * pu);  // ds_read_b64
    cx = cxy.x;
    cy = cxy.y;
    cz = s_zw[si][(pu >> 6) & 15];  // winner wave under interleaved mapping
  }
#undef MK
#undef KSEL

  __syncthreads();
  // bulk writeout of buffered indices
  for (int e = t; e < NCTR; e += 1024) fps_idx[b * NCTR + e] = fps_lds[e];
}

// ---------------------------------------------------------------------------
// Kernel 2: ball query. One wave per centroid; scan points in ascending index
// order, collect first 32 with dist <= r^2, pad with first hit.
// ---------------------------------------------------------------------------
__global__ __launch_bounds__(256) void ballq_kernel(const float* __restrict__ xyz,
                                                    const int* __restrict__ fps_idx,
                                                    int* __restrict__ ball_idx) {
  const int gw = (blockIdx.x * 256 + threadIdx.x) >> 6;  // 0..8191
  const int lane = threadIdx.x & 63;
  const int b = gw >> 10;
  const float* X = xyz + (size_t)b * 3 * NPTS;
  const float* Y = X + NPTS;
  const float* Z = X + 2 * NPTS;
  const int c = fps_idx[gw];
  const float cx = X[c], cy = Y[c], cz = Z[c];
  int* out = ball_idx + (size_t)gw * 32;
  const float R2 = 0.04f;

  int cnt = 0, first = -1;
  for (int base = 0; base < NPTS; base += 64) {
    const int j = base + lane;
    const float d = sq_dist(X[j], Y[j], Z[j], cx, cy, cz);
    const bool inb = !(d > R2);
    const unsigned long long m = __ballot(inb);
    if (first < 0 && m != 0ull) first = base + __ffsll(m) - 1;
    if (inb) {
      const int pos = cnt + __popcll(m & ((1ull << lane) - 1ull));
      if (pos < 32) out[pos] = j;
    }
    cnt += __popcll(m);
    if (cnt >= 32) break;
  }
  for (int k = cnt + lane; k < 32; k += 64) out[k] = first;
}

// ---------------------------------------------------------------------------
// Kernel 2b: one-off weight transpose into workspace: wt[c][o] layouts.
// ---------------------------------------------------------------------------
__global__ __launch_bounds__(256) void transpose_w_kernel(
    const float* __restrict__ w0, const float* __restrict__ w1,
    const float* __restrict__ w2, float* __restrict__ wt0,
    float* __restrict__ wt1, float* __restrict__ wt2) {
  const int t0 = blockIdx.x * 256 + threadIdx.x;
  const int stride = gridDim.x * 256;
  for (int e = t0; e < 64 * 67; e += stride) {
    int o = e / 67, c = e - o * 67;
    wt0[c * 64 + o] = w0[e];
  }
  for (int e = t0; e < 128 * 64; e += stride) {
    int o = e >> 6, c = e & 63;
    wt1[c * 128 + o] = w1[e];
  }
  for (int e = t0; e < 256 * 128; e += stride) {
    int o = e >> 7, c = e & 127;
    wt2[c * 256 + o] = w2[e];
  }
}

// ---------------------------------------------------------------------------
// Kernel 3: fused gather + 3-layer pointwise MLP + mean over 32 samples.
// R9: XCD-aware s-swizzle. out[(b*256+o)*1024+s] writes are 4B at 4KB
// stride; the 16 blocks sharing one 64B line were round-robined across
// XCDs (non-shared L2s) -> partial-line HBM write amplification. With
// s=(bx&7)*128+(bx>>3) each XCD owns a contiguous 128-s range, so all
// writers of any 16-aligned s-group share one L2 -> full-line writeback.
// ---------------------------------------------------------------------------
__global__ __launch_bounds__(256, 2) void mlp_kernel(
    const float* __restrict__ xyz, const float* __restrict__ points,
    const int* __restrict__ fps_idx, const int* __restrict__ ball_idx,
    const float* __restrict__ wt0, const float* __restrict__ b0,
    const float* __restrict__ wt1, const float* __restrict__ b1,
    const float* __restrict__ wt2, const float* __restrict__ b2,
    float* __restrict__ out) {
  const int bx = blockIdx.x, b = blockIdx.y, t = threadIdx.x;
  const int s = (bx & 7) * 128 + (bx >> 3);  // XCD-aware bijective swizzle

  __shared__ float A1[64 * 36];    // layer0 out [o][k]
  __shared__ float A2[128 * 36];   // layer1 out [o][k]
  __shared__ float S[8704];        // scratch: A0+Wt0 | Wt1 | Wt2 chunk
  __shared__ float bias_sh[256];
  __shared__ int jidx[32];
  __shared__ float ctr[3];

  const int g = b * NCTR + s;

  // phase 1: indices, centroid, Wt0 [67][68] (stride-1 writes), bias0
  if (t < 32) jidx[t] = ball_idx[(size_t)g * 32 + t];
  if (t < 3) ctr[t] = xyz[((size_t)b * 3 + t) * NPTS + fps_idx[g]];
  float* A0 = S;              // [67][36]
  float* Wt0 = S + 67 * 36;   // [67][68]
  for (int e = t; e < 67 * 64; e += 256) {
    int c = e >> 6, o = e & 63;
    Wt0[c * 68 + o] = wt0[e];  // global coalesced, LDS stride-1
  }
  if (t < 64) bias_sh[t] = b0[t];
  __syncthreads();

  // phase 2: gather A0 = [xyz_norm(3); points(64)] x 32 samples
  for (int e = t; e < 67 * 32; e += 256) {
    int c = e >> 5, k = e & 31;
    int j = jidx[k];
    float v;
    if (c < 3)
      v = xyz[((size_t)b * 3 + c) * NPTS + j] - ctr[c];
    else
      v = points[((size_t)b * 64 + (c - 3)) * NPTS + j];
    A0[c * 36 + k] = v;
  }
  __syncthreads();

  // phase 3: layer 0 (67 -> 64), tile 4k x 2o
  {
    const int o0 = (t & 31) * 2;
    const int k0 = (t >> 5) * 4;
    float acc[4][2] = {{0.f, 0.f}, {0.f, 0.f}, {0.f, 0.f}, {0.f, 0.f}};
    for (int c = 0; c < 67; ++c) {
      const float4 a = *(const float4*)(A0 + c * 36 + k0);
      const float wv0 = Wt0[c * 68 + o0];
      const float wv1 = Wt0[c * 68 + o0 + 1];
      acc[0][0] = fmaf(a.x, wv0, acc[0][0]);
      acc[1][0] = fmaf(a.y, wv0, acc[1][0]);
      acc[2][0] = fmaf(a.z, wv0, acc[2][0]);
      acc[3][0] = fmaf(a.w, wv0, acc[3][0]);
      acc[0][1] = fmaf(a.x, wv1, acc[0][1]);
      acc[1][1] = fmaf(a.y, wv1, acc[1][1]);
      acc[2][1] = fmaf(a.z, wv1, acc[2][1]);
      acc[3][1] = fmaf(a.w, wv1, acc[3][1]);
    }
#pragma unroll
    for (int i = 0; i < 2; ++i) {
      const float bb = bias_sh[o0 + i];
      float4 r;
      r.x = silu_f(acc[0][i] + bb);
      r.y = silu_f(acc[1][i] + bb);
      r.z = silu_f(acc[2][i] + bb);
      r.w = silu_f(acc[3][i] + bb);
      *(float4*)(A1 + (o0 + i) * 36 + k0) = r;
    }
  }
  __syncthreads();

  // phase 4: stage Wt1 [64][132] (stride-1 writes), bias1
  float* Wt1 = S;
  for (int e = t; e < 128 * 64; e += 256) {
    int c = e >> 7, o = e & 127;
    Wt1[c * 132 + o] = wt1[e];
  }
  if (t < 128) bias_sh[t] = b1[t];
  __syncthreads();

  // phase 5: layer 1 (64 -> 128), tile 4k x 4o
  {
    const int o0 = (t & 31) * 4;
    const int k0 = (t >> 5) * 4;
    float acc[4][4];
#pragma unroll
    for (int kk = 0; kk < 4; ++kk)
#pragma unroll
      for (int oo = 0; oo < 4; ++oo) acc[kk][oo] = 0.f;
    for (int c = 0; c < 64; ++c) {
      const float4 a = *(const float4*)(A1 + c * 36 + k0);
      const float4 w = *(const float4*)(Wt1 + c * 132 + o0);
      const float av[4] = {a.x, a.y, a.z, a.w};
      const float wv[4] = {w.x, w.y, w.z, w.w};
#pragma unroll
      for (int kk = 0; kk < 4; ++kk)
#pragma unroll
        for (int oo = 0; oo < 4; ++oo)
          acc[kk][oo] = fmaf(av[kk], wv[oo], acc[kk][oo]);
    }
#pragma unroll
    for (int oo = 0; oo < 4; ++oo) {
      const float bb = bias_sh[o0 + oo];
      float4 r;
      r.x = silu_f(acc[0][oo] + bb);
      r.y = silu_f(acc[1][oo] + bb);
      r.z = silu_f(acc[2][oo] + bb);
      r.w = silu_f(acc[3][oo] + bb);
      *(float4*)(A2 + (o0 + oo) * 36 + k0) = r;
    }
  }
  __syncthreads();

  // phase 6: layer 2 (128 -> 256) in 4 chunks of 64 outputs + mean over k
  float* Wt2 = S;   // [128][68] per chunk
  float* P = A1;    // partial sums [64][9] (A1 dead)
  const int o0 = (t & 31) * 2;
  const int k0 = (t >> 5) * 4;
  const int kg = t >> 5;
  for (int chunk = 0; chunk < 4; ++chunk) {
    for (int e = t; e < 64 * 128; e += 256) {
      int c = e >> 6, o = e & 63;
      Wt2[c * 68 + o] = wt2[c * 256 + chunk * 64 + o];  // coalesced / stride-1
    }
    if (t < 64) bias_sh[t] = b2[chunk * 64 + t];
    __syncthreads();

    float acc[4][2] = {{0.f, 0.f}, {0.f, 0.f}, {0.f, 0.f}, {0.f, 0.f}};
    for (int c = 0; c < 128; ++c) {
      const float4 a = *(const float4*)(A2 + c * 36 + k0);
      const float wv0 = Wt2[c * 68 + o0];
      const float wv1 = Wt2[c * 68 + o0 + 1];
      acc[0][0] = fmaf(a.x, wv0, acc[0][0]);
      acc[1][0] = fmaf(a.y, wv0, acc[1][0]);
      acc[2][0] = fmaf(a.z, wv0, acc[2][0]);
      acc[3][0] = fmaf(a.w, wv0, acc[3][0]);
      acc[0][1] = fmaf(a.x, wv1, acc[0][1]);
      acc[1][1] = fmaf(a.y, wv1, acc[1][1]);
      acc[2][1] = fmaf(a.z, wv1, acc[2][1]);
      acc[3][1] = fmaf(a.w, wv1, acc[3][1]);
    }
#pragma unroll
    for (int i = 0; i < 2; ++i) {
      const float bb = bias_sh[o0 + i];
      float sum = silu_f(acc[0][i] + bb) + silu_f(acc[1][i] + bb) +
                  silu_f(acc[2][i] + bb) + silu_f(acc[3][i] + bb);
      P[(o0 + i) * 9 + kg] = sum;
    }
    __syncthreads();
    if (t < 64) {
      float tot = 0.f;
#pragma unroll
      for (int q = 0; q < 8; ++q) tot += P[t * 9 + q];
      out[((size_t)b * 256 + chunk * 64 + t) * NCTR + s] = tot * (1.0f / 32.0f);
    }
    __syncthreads();
  }
}

extern "C" void kernel_launch(void* const* d_in, const int* in_sizes, int n_in,
                              void* d_out, int out_size, void* d_ws, size_t ws_size,
                              hipStream_t stream) {
  const float* xyz = (const float*)d_in[0];
  const float* points = (const float*)d_in[1];
  const float* w0 = (const float*)d_in[2];
  const float* b0 = (const float*)d_in[3];
  const float* w1 = (const float*)d_in[4];
  const float* b1 = (const float*)d_in[5];
  const float* w2 = (const float*)d_in[6];
  const float* b2 = (const float*)d_in[7];
  float* out = (float*)d_out;

  int* fps = (int*)d_ws;                       // 8K ints
  int* bidx = (int*)d_ws + 8192;               // 256K ints
  float* wt0 = (float*)d_ws + 270336;          // 67*64
  float* wt1 = wt0 + 67 * 64;                  // 64*128
  float* wt2 = wt1 + 64 * 128;                 // 128*256
  float* sxg = (float*)d_ws + 315584;          // 8*16384 sorted x
  float* syg = sxg + BATCH * NPTS;             // sorted y
  float* szg = syg + BATCH * NPTS;             // sorted z
  int* sog = (int*)(szg + BATCH * NPTS);       // sorted orig idx (~3.4 MB total)

  transpose_w_kernel<<<64, 256, 0, stream>>>(w0, w1, w2, wt0, wt1, wt2);
  sort_kernel<<<BATCH, 1024, 0, stream>>>(xyz, sxg, syg, szg, sog);
  fps_kernel<<<BATCH, 1024, 0, stream>>>(xyz, sxg, syg, szg, sog, fps);
  ballq_kernel<<<2048, 256, 0, stream>>>(xyz, fps, bidx);
  mlp_kernel<<<dim3(NCTR, BATCH), 256, 0, stream>>>(xyz, points, fps, bidx,
                                                    wt0, b0, wt1, b1, wt2, b2, out);
}